// Round 1
// baseline (477.869 us; speedup 1.0000x reference)
//
#include <hip/hip_runtime.h>
#include <hip/hip_bf16.h>

#define NREF 131072
#define NALT 32768
#define BSEG 4096
#define D 128
#define F 512
#define H 256
#define EPS 1e-5f

typedef short short8 __attribute__((ext_vector_type(8)));
typedef float f32x4 __attribute__((ext_vector_type(4)));

__device__ __forceinline__ float selu_f(float z) {
    const float sc = 1.0507009873554805f;
    const float al = 1.6732632423543772f;
    return z > 0.f ? sc * z : sc * al * (__expf(z) - 1.f);
}

// Pack fp32 KxN weight into bf16 MFMA B-fragment layout for 16x16x32:
// frag index ((nt*KT + kt)*64 + lane)*8 + j  <->  B[kt*32 + (lane>>4)*8 + j][nt*16 + (lane&15)]
__global__ void pack_w(const float* __restrict__ w, __bf16* __restrict__ wp, int KT, int N) {
    int idx = blockIdx.x * 256 + threadIdx.x;
    int j = idx & 7;
    int l = (idx >> 3) & 63;
    int t = idx >> 9;
    int kt = t % KT;
    int nt = t / KT;
    int k = kt * 32 + ((l >> 4) << 3) + j;
    int n = (nt << 4) + (l & 15);
    wp[idx] = (__bf16)w[k * N + n];
}

// Pass 1: LN1 -> half GEMM1 (z2 columns) -> SELU -> LN2 -> segment sums (atomics)
__global__ __launch_bounds__(256, 2)
void pass1_kernel(const float* __restrict__ x, const int* __restrict__ seg,
                  const __bf16* __restrict__ w1p, const float* __restrict__ b1,
                  const float* __restrict__ n1w, const float* __restrict__ n1b,
                  const float* __restrict__ n2w, const float* __restrict__ n2b,
                  float* __restrict__ seg_sum, float* __restrict__ seg_cnt) {
    __shared__ float xs[32][129];
    __shared__ __align__(16) __bf16 ys[32][136];
    __shared__ float z2s[32][257];
    __shared__ float n1w_s[D], n1b_s[D], n2w_s[H], n2b_s[H], b1_s[F];
    __shared__ int seg_s[32];

    const int tid = threadIdx.x;
    const size_t row0 = (size_t)blockIdx.x * 32;

    for (int i = 0; i < 4; ++i) {
        int idx = i * 1024 + tid * 4;
        const float4 v = *reinterpret_cast<const float4*>(x + row0 * D + idx);
        int r = idx >> 7, c = idx & 127;
        xs[r][c] = v.x; xs[r][c+1] = v.y; xs[r][c+2] = v.z; xs[r][c+3] = v.w;
    }
    if (tid < D) { n1w_s[tid] = n1w[tid]; n1b_s[tid] = n1b[tid]; }
    n2w_s[tid] = n2w[tid]; n2b_s[tid] = n2b[tid];
    b1_s[tid] = b1[tid]; b1_s[tid + 256] = b1[tid + 256];
    if (tid < 32) seg_s[tid] = seg[row0 + tid];
    __syncthreads();

    { // LN1: 8 threads/row x 16 cols
        int r = tid >> 3, g = tid & 7;
        float s = 0.f, ss = 0.f;
        for (int c = 0; c < 16; ++c) { float v = xs[r][g*16 + c]; s += v; ss += v * v; }
        s += __shfl_xor(s, 1); ss += __shfl_xor(ss, 1);
        s += __shfl_xor(s, 2); ss += __shfl_xor(ss, 2);
        s += __shfl_xor(s, 4); ss += __shfl_xor(ss, 4);
        float mean = s * (1.f/128.f);
        float var = ss * (1.f/128.f) - mean * mean;
        float rs = rsqrtf(var + EPS);
        for (int c = 0; c < 16; ++c) {
            int col = g*16 + c;
            ys[r][col] = (__bf16)((xs[r][col] - mean) * rs * n1w_s[col] + n1b_s[col]);
        }
    }
    __syncthreads();

    { // half GEMM1: out 32x256 (z2 columns 256..511 of F)
        int wv = tid >> 6, lane = tid & 63;
        int mt = wv & 1, nq = wv >> 1;
        int mrow = mt*16 + (lane & 15);
        short8 a[4];
        for (int kt = 0; kt < 4; ++kt)
            a[kt] = *reinterpret_cast<const short8*>(&ys[mrow][kt*32 + ((lane >> 4) << 3)]);
        for (int nt = 0; nt < 8; ++nt) {
            int nt_g = 16 + nq*8 + nt;
            f32x4 acc = {0.f, 0.f, 0.f, 0.f};
            for (int kt = 0; kt < 4; ++kt) {
                short8 b = *reinterpret_cast<const short8*>(w1p + ((size_t)(nt_g*4 + kt)*64 + lane)*8);
                acc = __builtin_amdgcn_mfma_f32_16x16x32_bf16(a[kt], b, acc, 0, 0, 0);
            }
            int cl = nq*128 + nt*16 + (lane & 15);
            float bb = b1_s[256 + cl];
            for (int reg = 0; reg < 4; ++reg) {
                int row = mt*16 + ((lane >> 4) << 2) + reg;
                z2s[row][cl] = selu_f(acc[reg] + bb);
            }
        }
    }
    __syncthreads();

    { // LN2 in place: 8 threads/row x 32 cols
        int r = tid >> 3, g = tid & 7;
        float s = 0.f, ss = 0.f;
        for (int c = 0; c < 32; ++c) { float v = z2s[r][g*32 + c]; s += v; ss += v * v; }
        s += __shfl_xor(s, 1); ss += __shfl_xor(ss, 1);
        s += __shfl_xor(s, 2); ss += __shfl_xor(ss, 2);
        s += __shfl_xor(s, 4); ss += __shfl_xor(ss, 4);
        float mean = s * (1.f/256.f);
        float var = ss * (1.f/256.f) - mean * mean;
        float rs = rsqrtf(var + EPS);
        for (int c = 0; c < 32; ++c) {
            int col = g*32 + c;
            z2s[r][col] = (z2s[r][col] - mean) * rs * n2w_s[col] + n2b_s[col];
        }
    }
    __syncthreads();

    { // segment accumulate: thread = column, run-length compress (segments sorted)
        int c = tid;
        int s_cur = seg_s[0];
        float run = 0.f;
        for (int r = 0; r < 32; ++r) {
            int sg = seg_s[r];
            if (sg != s_cur) {
                atomicAdd(&seg_sum[(size_t)s_cur * H + c], run);
                run = 0.f; s_cur = sg;
            }
            run += z2s[r][c];
        }
        atomicAdd(&seg_sum[(size_t)s_cur * H + c], run);
        if (tid == 0) {
            int sc = seg_s[0]; float rl = 0.f;
            for (int r = 0; r < 32; ++r) {
                if (seg_s[r] != sc) { atomicAdd(&seg_cnt[sc], rl); rl = 0.f; sc = seg_s[r]; }
                rl += 1.f;
            }
            atomicAdd(&seg_cnt[sc], rl);
        }
    }
}

// Per-segment gate offsets: G_ref = beta_ref*mf_ref ; G_alt = beta_alt*mf_alt + gamma*mf_ref
__global__ void mf_kernel(const float* __restrict__ sum_r, const float* __restrict__ cnt_r,
                          const float* __restrict__ sum_a, const float* __restrict__ cnt_a,
                          const float* __restrict__ regz, const float* __restrict__ reg_w_pre,
                          const float* __restrict__ beta_ref, const float* __restrict__ beta_alt,
                          const float* __restrict__ gamma,
                          float* __restrict__ G_ref, float* __restrict__ G_alt) {
    int s = blockIdx.x, c = threadIdx.x;
    size_t i = (size_t)s * H + c;
    float rw = __expf(reg_w_pre[0]) + 0.25f;
    float mfr = (sum_r[i] + rw * regz[c]) / (cnt_r[s] + rw);
    float mfa = sum_a[i] / fmaxf(cnt_a[s], 1.f);
    G_ref[i] = beta_ref[0] * mfr;
    G_alt[i] = beta_alt[0] * mfa + gamma[0] * mfr;
}

// Pass 2: LN1 -> GEMM1 -> SELU -> LN2 -> gate -> GEMM2 -> +x +b2 -> out
__global__ __launch_bounds__(256, 2)
void pass2_kernel(const float* __restrict__ x, const int* __restrict__ seg,
                  const __bf16* __restrict__ w1p, const float* __restrict__ b1,
                  const __bf16* __restrict__ w2p, const float* __restrict__ b2,
                  const float* __restrict__ n1w, const float* __restrict__ n1b,
                  const float* __restrict__ n2w, const float* __restrict__ n2b,
                  const float* __restrict__ alpha_p, const float* __restrict__ G,
                  float* __restrict__ out) {
    __shared__ float xs[32][129];
    __shared__ __align__(16) __bf16 ys[32][136];
    __shared__ __align__(16) __bf16 zs[32][520];
    __shared__ float n1w_s[D], n1b_s[D], n2w_s[H], n2b_s[H], b1_s[F], b2_s[D];
    __shared__ int seg_s[32];
    __shared__ float alpha_s;

    const int tid = threadIdx.x;
    const size_t row0 = (size_t)blockIdx.x * 32;

    for (int i = 0; i < 4; ++i) {
        int idx = i * 1024 + tid * 4;
        const float4 v = *reinterpret_cast<const float4*>(x + row0 * D + idx);
        int r = idx >> 7, c = idx & 127;
        xs[r][c] = v.x; xs[r][c+1] = v.y; xs[r][c+2] = v.z; xs[r][c+3] = v.w;
    }
    if (tid < D) { n1w_s[tid] = n1w[tid]; n1b_s[tid] = n1b[tid]; b2_s[tid] = b2[tid]; }
    n2w_s[tid] = n2w[tid]; n2b_s[tid] = n2b[tid];
    b1_s[tid] = b1[tid]; b1_s[tid + 256] = b1[tid + 256];
    if (tid < 32) seg_s[tid] = seg[row0 + tid];
    if (tid == 0) alpha_s = alpha_p[0];
    __syncthreads();

    { // LN1
        int r = tid >> 3, g = tid & 7;
        float s = 0.f, ss = 0.f;
        for (int c = 0; c < 16; ++c) { float v = xs[r][g*16 + c]; s += v; ss += v * v; }
        s += __shfl_xor(s, 1); ss += __shfl_xor(ss, 1);
        s += __shfl_xor(s, 2); ss += __shfl_xor(ss, 2);
        s += __shfl_xor(s, 4); ss += __shfl_xor(ss, 4);
        float mean = s * (1.f/128.f);
        float var = ss * (1.f/128.f) - mean * mean;
        float rs = rsqrtf(var + EPS);
        for (int c = 0; c < 16; ++c) {
            int col = g*16 + c;
            ys[r][col] = (__bf16)((xs[r][col] - mean) * rs * n1w_s[col] + n1b_s[col]);
        }
    }
    __syncthreads();

    { // GEMM1 full: 32x512
        int wv = tid >> 6, lane = tid & 63;
        int mt = wv & 1, nh = wv >> 1;
        int mrow = mt*16 + (lane & 15);
        short8 a[4];
        for (int kt = 0; kt < 4; ++kt)
            a[kt] = *reinterpret_cast<const short8*>(&ys[mrow][kt*32 + ((lane >> 4) << 3)]);
        for (int nt = 0; nt < 16; ++nt) {
            int nt_g = nh*16 + nt;
            f32x4 acc = {0.f, 0.f, 0.f, 0.f};
            for (int kt = 0; kt < 4; ++kt) {
                short8 b = *reinterpret_cast<const short8*>(w1p + ((size_t)(nt_g*4 + kt)*64 + lane)*8);
                acc = __builtin_amdgcn_mfma_f32_16x16x32_bf16(a[kt], b, acc, 0, 0, 0);
            }
            int col = nt_g*16 + (lane & 15);
            float bb = b1_s[col];
            for (int reg = 0; reg < 4; ++reg) {
                int row = mt*16 + ((lane >> 4) << 2) + reg;
                zs[row][col] = (__bf16)selu_f(acc[reg] + bb);
            }
        }
    }
    __syncthreads();

    { // LN2 on z2 (cols 256..511) + gate, write A2 = z1*gate in place over z1
        int r = tid >> 3, g = tid & 7;
        float s = 0.f, ss = 0.f;
        for (int c = 0; c < 32; ++c) { float v = (float)zs[r][256 + g*32 + c]; s += v; ss += v * v; }
        s += __shfl_xor(s, 1); ss += __shfl_xor(ss, 1);
        s += __shfl_xor(s, 2); ss += __shfl_xor(ss, 2);
        s += __shfl_xor(s, 4); ss += __shfl_xor(ss, 4);
        float mean = s * (1.f/256.f);
        float var = ss * (1.f/256.f) - mean * mean;
        float rs = rsqrtf(var + EPS);
        const float* Grow = G + (size_t)seg_s[r] * H;
        for (int c = 0; c < 32; ++c) {
            int col = g*32 + c;
            float z2n = ((float)zs[r][256 + col] - mean) * rs * n2w_s[col] + n2b_s[col];
            float gate = z2n * alpha_s + 1.f + Grow[col];
            zs[r][col] = (__bf16)((float)zs[r][col] * gate);
        }
    }
    __syncthreads();

    { // GEMM2: (32x256)@(256x128), accumulate into xs (residual) + b2
        int wv = tid >> 6, lane = tid & 63;
        int mt = wv & 1, nq = wv >> 1;
        int mrow = mt*16 + (lane & 15);
        short8 a[8];
        for (int kt = 0; kt < 8; ++kt)
            a[kt] = *reinterpret_cast<const short8*>(&zs[mrow][kt*32 + ((lane >> 4) << 3)]);
        for (int nt = 0; nt < 4; ++nt) {
            int nt_g = nq*4 + nt;
            f32x4 acc = {0.f, 0.f, 0.f, 0.f};
            for (int kt = 0; kt < 8; ++kt) {
                short8 b = *reinterpret_cast<const short8*>(w2p + ((size_t)(nt_g*8 + kt)*64 + lane)*8);
                acc = __builtin_amdgcn_mfma_f32_16x16x32_bf16(a[kt], b, acc, 0, 0, 0);
            }
            int col = nt_g*16 + (lane & 15);
            for (int reg = 0; reg < 4; ++reg) {
                int row = mt*16 + ((lane >> 4) << 2) + reg;
                xs[row][col] += acc[reg] + b2_s[col];
            }
        }
    }
    __syncthreads();

    for (int i = 0; i < 4; ++i) {
        int idx = i * 1024 + tid * 4;
        int r = idx >> 7, c = idx & 127;
        float4 v;
        v.x = xs[r][c]; v.y = xs[r][c+1]; v.z = xs[r][c+2]; v.w = xs[r][c+3];
        *reinterpret_cast<float4*>(out + row0 * D + idx) = v;
    }
}

extern "C" void kernel_launch(void* const* d_in, const int* in_sizes, int n_in,
                              void* d_out, int out_size, void* d_ws, size_t ws_size,
                              hipStream_t stream) {
    const float* ref_flat = (const float*)d_in[0];
    const float* alt_flat = (const float*)d_in[1];
    const int*   ref_seg  = (const int*)d_in[2];
    const int*   alt_seg  = (const int*)d_in[3];
    const float* norm1_w  = (const float*)d_in[4];
    const float* norm1_b  = (const float*)d_in[5];
    const float* w1_ref   = (const float*)d_in[6];
    const float* b1_ref   = (const float*)d_in[7];
    const float* w1_alt   = (const float*)d_in[8];
    const float* b1_alt   = (const float*)d_in[9];
    const float* norm2_w  = (const float*)d_in[10];
    const float* norm2_b  = (const float*)d_in[11];
    const float* alpha_ref = (const float*)d_in[12];
    const float* alpha_alt = (const float*)d_in[13];
    const float* beta_ref  = (const float*)d_in[14];
    const float* beta_alt  = (const float*)d_in[15];
    const float* gamma     = (const float*)d_in[16];
    const float* ref_regularizer = (const float*)d_in[17];
    const float* reg_w_pre = (const float*)d_in[18];
    const float* w2_ref   = (const float*)d_in[19];
    const float* b2_ref   = (const float*)d_in[20];
    const float* w2_alt   = (const float*)d_in[21];
    const float* b2_alt   = (const float*)d_in[22];

    char* ws = (char*)d_ws;
    float* sum_r = (float*)(ws);                      // 4 MB
    float* sum_a = (float*)(ws + 4194304);            // 4 MB
    float* cnt_r = (float*)(ws + 8388608);            // 16 KB
    float* cnt_a = (float*)(ws + 8404992);            // 16 KB
    float* G_ref = (float*)(ws + 8421376);            // 4 MB
    float* G_alt = (float*)(ws + 12615680);           // 4 MB
    __bf16* w1p_r = (__bf16*)(ws + 16809984);         // 128 KB
    __bf16* w1p_a = (__bf16*)(ws + 16941056);         // 128 KB
    __bf16* w2p_r = (__bf16*)(ws + 17072128);         // 64 KB
    __bf16* w2p_a = (__bf16*)(ws + 17137664);         // 64 KB

    hipMemsetAsync(d_ws, 0, 8421376, stream);  // zero sums + counts (atomic targets)

    pack_w<<<256, 256, 0, stream>>>(w1_ref, w1p_r, 4, F);
    pack_w<<<256, 256, 0, stream>>>(w1_alt, w1p_a, 4, F);
    pack_w<<<128, 256, 0, stream>>>(w2_ref, w2p_r, 8, D);
    pack_w<<<128, 256, 0, stream>>>(w2_alt, w2p_a, 8, D);

    pass1_kernel<<<NREF/32, 256, 0, stream>>>(ref_flat, ref_seg, w1p_r, b1_ref,
                                              norm1_w, norm1_b, norm2_w, norm2_b, sum_r, cnt_r);
    pass1_kernel<<<NALT/32, 256, 0, stream>>>(alt_flat, alt_seg, w1p_a, b1_alt,
                                              norm1_w, norm1_b, norm2_w, norm2_b, sum_a, cnt_a);

    mf_kernel<<<BSEG, 256, 0, stream>>>(sum_r, cnt_r, sum_a, cnt_a, ref_regularizer, reg_w_pre,
                                        beta_ref, beta_alt, gamma, G_ref, G_alt);

    pass2_kernel<<<NREF/32, 256, 0, stream>>>(ref_flat, ref_seg, w1p_r, b1_ref, w2p_r, b2_ref,
                                              norm1_w, norm1_b, norm2_w, norm2_b,
                                              alpha_ref, G_ref, (float*)d_out);
    pass2_kernel<<<NALT/32, 256, 0, stream>>>(alt_flat, alt_seg, w1p_a, b1_alt, w2p_a, b2_alt,
                                              norm1_w, norm1_b, norm2_w, norm2_b,
                                              alpha_alt, G_alt, (float*)d_out + (size_t)NREF * D);
}